// Round 18
// baseline (223.923 us; speedup 1.0000x reference)
//
#include <hip/hip_runtime.h>
#include <hip/hip_bf16.h>
#include <stdint.h>

#define DEV static __device__ __forceinline__

using f32x4  = __attribute__((ext_vector_type(4))) float;
using bf16x4 = __attribute__((ext_vector_type(4))) __bf16;
using bf16x8 = __attribute__((ext_vector_type(8))) __bf16;

constexpr int SEQ = 2048;

DEV unsigned short f2bf(float f) {
  union { float f; unsigned u; } c; c.f = f;
  unsigned u = c.u;
  u += 0x7fffu + ((u >> 16) & 1u);   // RNE
  return (unsigned short)(u >> 16);
}
DEV float bf2f(unsigned short h) {
  union { unsigned u; float f; } c; c.u = ((unsigned)h) << 16;
  return c.f;
}

DEV float wred_sum(float v) {
  #pragma unroll
  for (int m = 32; m > 0; m >>= 1) v += __shfl_xor(v, m, 64);
  return v;
}

// async global->LDS, 16B per lane. LDS dest = wave-uniform base + lane*16.
DEV void g2l16(const unsigned short* g, unsigned short* l) {
  __builtin_amdgcn_global_load_lds(
      (const __attribute__((address_space(1))) void*)g,
      (__attribute__((address_space(3))) void*)l, 16, 0, 0);
}

// T1: bijective chunked XCD swizzle (requires nwg % 8 == 0)
DEV int xcd_map(int bid, int nwg) {
  const int cpx = nwg >> 3;
  return (bid & 7) * cpx + (bid >> 3);
}

// ---------------- ALL weight transposes, one dispatch, 64x64 tiles ----------
__global__ __launch_bounds__(256) void convw_all(
    const float* __restrict__ Wq, const float* __restrict__ Wk,
    const float* __restrict__ Wv, const float* __restrict__ Wo,
    const float* __restrict__ W1, const float* __restrict__ W2,
    unsigned short* __restrict__ WqkvT, unsigned short* __restrict__ WoT,
    unsigned short* __restrict__ W1T,   unsigned short* __restrict__ W2T)
{
  const int blk = blockIdx.x;
  const float* inh; unsigned short* outh; int K, Nh, n0, k0;
  if (blk < 768) {
    const int seg = blk >> 8, l = blk & 255;       // 16 heads x 16 k-tiles
    const int head = l >> 4, kt = l & 15;
    const float* in = seg == 0 ? Wq : seg == 1 ? Wk : Wv;
    inh  = in + (size_t)head * 1024 * 64;
    outh = WqkvT + (size_t)seg * 1024 * 1024 + (size_t)head * 64 * 1024;
    K = 1024; Nh = 64; n0 = 0; k0 = kt * 64;
  } else if (blk < 1024) {
    const int l = blk - 768; inh = Wo; outh = WoT; K = 1024; Nh = 1024;
    n0 = (l & 15) * 64; k0 = (l >> 4) * 64;
  } else if (blk < 2048) {
    const int l = blk - 1024; inh = W1; outh = W1T; K = 1024; Nh = 4096;
    n0 = (l & 63) * 64; k0 = (l >> 6) * 64;
  } else {
    const int l = blk - 2048; inh = W2; outh = W2T; K = 4096; Nh = 1024;
    n0 = (l & 15) * 64; k0 = (l >> 4) * 64;
  }
  __shared__ float t[64][65];
  const int tid = threadIdx.x;
  #pragma unroll
  for (int r = 0; r < 4; ++r) {
    const int idx = tid + 256 * r;
    const int k = idx >> 4, c = (idx & 15) * 4;
    const float4 v = *(const float4*)(inh + (size_t)(k0 + k) * Nh + n0 + c);
    t[c + 0][k] = v.x; t[c + 1][k] = v.y; t[c + 2][k] = v.z; t[c + 3][k] = v.w;
  }
  __syncthreads();
  #pragma unroll
  for (int r = 0; r < 4; ++r) {
    const int idx = tid + 256 * r;
    const int n = idx >> 4, k4 = (idx & 15) * 4;
    ushort4 o;
    o.x = f2bf(t[n][k4 + 0]); o.y = f2bf(t[n][k4 + 1]);
    o.z = f2bf(t[n][k4 + 2]); o.w = f2bf(t[n][k4 + 3]);
    *(ushort4*)(outh + (size_t)(n0 + n) * K + k0 + k4) = o;
  }
}

// ---------------- LayerNorm -> bf16 out (templated input dtype) -------------
template<bool BF16IN>
__global__ __launch_bounds__(256) void ln_kernel(
    const void* __restrict__ xin, const float* __restrict__ w,
    const float* __restrict__ b, unsigned short* __restrict__ out)
{
  const int row = blockIdx.x;
  const int tid = threadIdx.x;
  float4 v;
  if (BF16IN) {
    const ushort4 u = ((const ushort4*)((const unsigned short*)xin + (size_t)row * 1024))[tid];
    v.x = bf2f(u.x); v.y = bf2f(u.y); v.z = bf2f(u.z); v.w = bf2f(u.w);
  } else {
    v = ((const float4*)((const float*)xin + (size_t)row * 1024))[tid];
  }
  float s  = v.x + v.y + v.z + v.w;
  float s2 = v.x*v.x + v.y*v.y + v.z*v.z + v.w*v.w;
  s = wred_sum(s); s2 = wred_sum(s2);
  __shared__ float rs[4], rs2[4];
  const int wave = tid >> 6, lane = tid & 63;
  if (lane == 0) { rs[wave] = s; rs2[wave] = s2; }
  __syncthreads();
  const float S  = rs[0] + rs[1] + rs[2] + rs[3];
  const float S2 = rs2[0] + rs2[1] + rs2[2] + rs2[3];
  const float mean = S * (1.f / 1024.f);
  const float var  = S2 * (1.f / 1024.f) - mean * mean;
  const float inv  = rsqrtf(var + 1e-5f);
  const float4 wv = ((const float4*)w)[tid];
  const float4 bv = ((const float4*)b)[tid];
  ushort4 o;
  o.x = f2bf((v.x - mean) * inv * wv.x + bv.x);
  o.y = f2bf((v.y - mean) * inv * wv.y + bv.y);
  o.z = f2bf((v.z - mean) * inv * wv.z + bv.z);
  o.w = f2bf((v.w - mean) * inv * wv.w + bv.w);
  ((ushort4*)(out + (size_t)row * 1024))[tid] = o;
}

// ---------------- 128x128 K-pipelined GEMM, BK=64 (Wo / FFN2) ---------------
// 4 waves (2x2), wave -> 64x64 out (32 MFMA : 16 ds_read = 2.0 ratio, fixes
// the LDS-pipe saturation of the old 64x32 wave tile). 3-slot LDS = 96 KB
// (1 block/CU), 8 loads/stage/thread, counted vmcnt(8) (stage t landed,
// stage t+1 in flight, 2-iter prefetch distance), one raw s_barrier/iter.
// EPI 2: bf16 out = acc + bias + fp32 res   (Wo -> x1h)
// EPI 3: fp32 out = acc + bias + bf16 res   (FFN2 -> d_out)
template<int EPI>
__global__ __launch_bounds__(256) void gemm_kp(
    const unsigned short* __restrict__ A, const unsigned short* __restrict__ BT,
    void* __restrict__ Cout, const float* __restrict__ bias,
    const float* __restrict__ resf, const unsigned short* __restrict__ resh,
    int M, int N, int K)
{
  __shared__ unsigned short sA[3][128 * 64];
  __shared__ unsigned short sB[3][128 * 64];
  const int tid = threadIdx.x;
  const int wave = tid >> 6, lane = tid & 63;
  const int wr = wave >> 1, wc = wave & 1;       // 2x2 waves -> 64x64 each
  const int bid = xcd_map(blockIdx.y * gridDim.x + blockIdx.x, gridDim.x * gridDim.y);
  const int m0 = (bid / gridDim.x) * 128, n0 = (bid % gridDim.x) * 128;
  const int lr = lane & 15, lg = lane >> 4;
  const int wb = tid & 192;                      // wave*64 (uniform)

  const f32x4 zero = {0.f, 0.f, 0.f, 0.f};
  f32x4 acc[4][4];
  #pragma unroll
  for (int i = 0; i < 4; ++i)
    #pragma unroll
    for (int j = 0; j < 4; ++j) acc[i][j] = zero;

  // 8 g2l16/thread/stage (A: 4 rounds, B: 4 rounds); 128x64 each
  auto STAGE = [&](int slot, int kt) {
    const int k0 = kt * 64;
    #pragma unroll
    for (int r = 0; r < 4; ++r) {
      const int c = tid + 256 * r;
      const int row = c >> 3;
      const int so = ((c & 7) ^ (row & 7)) * 8;
      const int cb = wb + 256 * r;
      g2l16(A  + (size_t)(m0 + row) * K + k0 + so, sA[slot] + (size_t)cb * 8);
      g2l16(BT + (size_t)(n0 + row) * K + k0 + so, sB[slot] + (size_t)cb * 8);
    }
  };

  const int nt = K / 64;
  STAGE(0, 0); STAGE(1, 1);

  for (int t = 0; t < nt; ++t) {
    asm volatile("s_waitcnt vmcnt(8)" ::: "memory");   // stage t landed (8 loads/stage)
    __builtin_amdgcn_s_barrier();                      // all waves' loads in
    const int slot = t % 3;
    bf16x8 af[4][2], bfr[4][2];
    #pragma unroll
    for (int i = 0; i < 4; ++i) {
      const int row = wr * 64 + i * 16 + lr;
      #pragma unroll
      for (int kk = 0; kk < 2; ++kk)
        af[i][kk] = *(const bf16x8*)(sA[slot] + row * 64 + (((kk * 4 + lg) ^ (row & 7)) << 3));
    }
    #pragma unroll
    for (int j = 0; j < 4; ++j) {
      const int row = wc * 64 + j * 16 + lr;
      #pragma unroll
      for (int kk = 0; kk < 2; ++kk)
        bfr[j][kk] = *(const bf16x8*)(sB[slot] + row * 64 + (((kk * 4 + lg) ^ (row & 7)) << 3));
    }
    __builtin_amdgcn_s_setprio(1);
    #pragma unroll
    for (int i = 0; i < 4; ++i)
      #pragma unroll
      for (int j = 0; j < 4; ++j)
        #pragma unroll
        for (int kk = 0; kk < 2; ++kk)
          acc[i][j] = __builtin_amdgcn_mfma_f32_16x16x32_bf16(af[i][kk], bfr[j][kk], acc[i][j], 0, 0, 0);
    __builtin_amdgcn_s_setprio(0);
    const int nx = (t + 2 < nt) ? t + 2 : nt - 1;      // clamped tail
    STAGE((t + 2) % 3, nx);
  }
  asm volatile("s_waitcnt vmcnt(0)" ::: "memory");

  #pragma unroll
  for (int i = 0; i < 4; ++i) {
    #pragma unroll
    for (int j = 0; j < 4; ++j) {
      #pragma unroll
      for (int r = 0; r < 4; ++r) {
        const int row = m0 + wr * 64 + i * 16 + lg * 4 + r;
        const int col = n0 + wc * 64 + j * 16 + lr;
        const float v = acc[i][j][r];
        if (EPI == 2) {
          ((unsigned short*)Cout)[(size_t)row * N + col] =
              f2bf(v + bias[col] + resf[(size_t)row * N + col]);
        } else {
          ((float*)Cout)[(size_t)row * N + col] =
              v + bias[col] + bf2f(resh[(size_t)row * N + col]);
        }
      }
    }
  }
}

// ---------------- 256x256 3-slot K-pipelined GEMM, BK=32 (QKV / FFN1) -------
template<int EPI>
__global__ __launch_bounds__(512) void gemm256v2(
    const unsigned short* __restrict__ A, const unsigned short* __restrict__ BT,
    void* __restrict__ Cout, const float* __restrict__ bias,
    int M, int N, int K)
{
  __shared__ unsigned short sA[3][256 * 32];
  __shared__ unsigned short sB[3][256 * 32];
  const int tid = threadIdx.x;
  const int wave = tid >> 6, lane = tid & 63;
  const int wm = wave >> 2, wn = wave & 3;       // 2x4 waves -> 128x64 each
  const int bid = xcd_map(blockIdx.y * gridDim.x + blockIdx.x, gridDim.x * gridDim.y);
  const int m0 = (bid / gridDim.x) * 256, n0 = (bid % gridDim.x) * 256;
  const int lr = lane & 15, lg = lane >> 4;
  const int wb = tid & 448;                      // wave*64 (uniform)

  const f32x4 zero = {0.f, 0.f, 0.f, 0.f};
  f32x4 acc[8][4];
  #pragma unroll
  for (int i = 0; i < 8; ++i)
    #pragma unroll
    for (int j = 0; j < 4; ++j) acc[i][j] = zero;

  auto STAGE = [&](int slot, int kt) {
    const int k0 = kt * 32;
    #pragma unroll
    for (int r = 0; r < 2; ++r) {
      const int c = tid + 512 * r;
      const int row = c >> 2;
      const int so = ((c & 3) ^ (row & 3)) * 8;
      const int cb = wb + 512 * r;
      g2l16(A  + (size_t)(m0 + row) * K + k0 + so, sA[slot] + (size_t)cb * 8);
      g2l16(BT + (size_t)(n0 + row) * K + k0 + so, sB[slot] + (size_t)cb * 8);
    }
  };

  const int nt = K / 32;
  STAGE(0, 0); STAGE(1, 1);

  for (int t = 0; t < nt; ++t) {
    asm volatile("s_waitcnt vmcnt(4)" ::: "memory");   // stage t landed (4 loads/stage)
    __builtin_amdgcn_s_barrier();                      // all waves' loads in
    const int slot = t % 3;
    bf16x8 af[8], bfr[4];
    #pragma unroll
    for (int i = 0; i < 8; ++i) {
      const int row = wm * 128 + i * 16 + lr;
      af[i] = *(const bf16x8*)(sA[slot] + row * 32 + ((lg ^ (row & 3)) << 3));
    }
    #pragma unroll
    for (int j = 0; j < 4; ++j) {
      const int row = wn * 64 + j * 16 + lr;
      bfr[j] = *(const bf16x8*)(sB[slot] + row * 32 + ((lg ^ (row & 3)) << 3));
    }
    __builtin_amdgcn_s_setprio(1);
    #pragma unroll
    for (int i = 0; i < 8; ++i)
      #pragma unroll
      for (int j = 0; j < 4; ++j)
        acc[i][j] = __builtin_amdgcn_mfma_f32_16x16x32_bf16(af[i], bfr[j], acc[i][j], 0, 0, 0);
    __builtin_amdgcn_s_setprio(0);
    const int nx = (t + 2 < nt) ? t + 2 : nt - 1;      // clamped tail
    STAGE((t + 2) % 3, nx);
  }
  asm volatile("s_waitcnt vmcnt(0)" ::: "memory");

  #pragma unroll
  for (int i = 0; i < 8; ++i) {
    #pragma unroll
    for (int j = 0; j < 4; ++j) {
      #pragma unroll
      for (int r = 0; r < 4; ++r) {
        const int row = m0 + wm * 128 + i * 16 + lg * 4 + r;
        const int col = n0 + wn * 64 + j * 16 + lr;
        float v = acc[i][j][r];
        if (EPI == 0) {
          if (col < 1024) v *= 0.18033688f;   // fold attn scale into Q
          ((unsigned short*)Cout)[(size_t)row * N + col] = f2bf(v);
        } else {
          float t2 = v + bias[col];
          t2 = t2 > 0.f ? t2 : 0.f;
          ((unsigned short*)Cout)[(size_t)row * N + col] = f2bf(t2);
        }
      }
    }
  }
}

// ---------------- MFMA flash attention (8-wave, merged q-pair) ----------------
constexpr int VPAD = 136;   // V/P row stride: 128 keys + 8

__global__ __launch_bounds__(512) void attn_mfma(
    const unsigned short* __restrict__ qkv, unsigned short* __restrict__ o)
{
  const int p  = blockIdx.x >> 5;          // 0..15 (p=0 heaviest, first)
  const int bh = blockIdx.x & 31;
  const int b = bh >> 4, h = bh & 15;
  const int tid = threadIdx.x;
  const int wave = tid >> 6, lane = tid & 63;
  const int grp = wave >> 2, wv = wave & 3;
  const int lr = lane & 15, lg = lane >> 4;

  const int qi = grp ? p : (31 - p);       // grp0 = long group
  const int mynt = (qi >> 1) + 1;          // causal 128-key tiles for this group
  const int nt_long = ((31 - p) >> 1) + 1; // block loop count
  const int q0 = qi * 64;

  __shared__ unsigned short Ks[128 * 64];      // linear, XOR-swizzled cols
  __shared__ unsigned short Vs[64 * VPAD];     // Vs[d][key] (transposed)
  __shared__ unsigned short Ps[8][16 * VPAD];  // per-wave P tile [q][key]

  const size_t qbase = ((size_t)(b * SEQ + q0 + wv * 16 + lr)) * 3072 + h * 64;
  bf16x8 qb[2];
  qb[0] = *(const bf16x8*)(qkv + qbase + lg * 8);
  qb[1] = *(const bf16x8*)(qkv + qbase + 32 + lg * 8);

  const f32x4 zero = {0.f, 0.f, 0.f, 0.f};
  f32x4 o_acc[4];
  #pragma unroll
  for (int dn = 0; dn < 4; ++dn) o_acc[dn] = zero;
  float m_run = -1e30f, l_run = 0.f;       // per-lane: q-row = lr

  for (int t = 0; t < nt_long; ++t) {
    const int j0 = t * 128;
    __syncthreads();                       // protect prev-tile reads
    #pragma unroll
    for (int r = 0; r < 2; ++r) {
      const int c = tid + 512 * r;
      const int row = c >> 3;
      const int slot = (c & 7) ^ (row & 7);
      const size_t gsrc = ((size_t)(b * SEQ + j0 + row)) * 3072 + 1024 + h * 64 + slot * 8;
      g2l16(qkv + gsrc, Ks + (size_t)((tid & 448) + 512 * r) * 8);
    }
    #pragma unroll
    for (int r = 0; r < 2; ++r) {
      const int c = tid + 512 * r;
      const int key = c & 127, dseg = c >> 7;
      const size_t base = ((size_t)(b * SEQ + j0 + key)) * 3072 + 2048 + h * 64 + dseg * 8;
      int4 rv = *(const int4*)(qkv + base);
      const unsigned short* u = (const unsigned short*)&rv;
      #pragma unroll
      for (int e = 0; e < 8; ++e) Vs[(dseg * 8 + e) * VPAD + key] = u[e];
    }
    __syncthreads();                       // staging visible (vmcnt+lgkm drain)

    if (t < mynt) {                        // group-uniform causal gate
      // ---- QK^T swapped: D[key'=lg*4+r][q'=lr] = mfma(K, Q) ----
      f32x4 s[8];
      __builtin_amdgcn_s_setprio(1);
      #pragma unroll
      for (int n = 0; n < 8; ++n) {
        const int row = n * 16 + lr;
        const bf16x8 kf0 = *(const bf16x8*)(Ks + row * 64 + ((lg ^ (row & 7)) << 3));
        const bf16x8 kf1 = *(const bf16x8*)(Ks + row * 64 + (((4 + lg) ^ (row & 7)) << 3));
        s[n] = __builtin_amdgcn_mfma_f32_16x16x32_bf16(kf0, qb[0], zero, 0, 0, 0);
        s[n] = __builtin_amdgcn_mfma_f32_16x16x32_bf16(kf1, qb[1], s[n], 0, 0, 0);
      }
      __builtin_amdgcn_s_setprio(0);

      // ---- online softmax: mask only on diag tile; defer-max (T13) ----
      const bool diag = (t == mynt - 1);
      float zm = -3e38f;
      if (diag) {
        const int q = q0 + wv * 16 + lr;
        const int kbase = j0 + lg * 4;
        #pragma unroll
        for (int n = 0; n < 8; ++n)
          #pragma unroll
          for (int r = 0; r < 4; ++r) {
            float z = s[n][r];
            if (kbase + n * 16 + r > q) z = -3e38f;
            s[n][r] = z;
            zm = fmaxf(zm, z);
          }
      } else {
        #pragma unroll
        for (int n = 0; n < 8; ++n)
          zm = fmaxf(fmaxf(fmaxf(zm, s[n][0]), fmaxf(s[n][1], s[n][2])), s[n][3]);
      }
      zm = fmaxf(zm, __shfl_xor(zm, 16, 64));
      zm = fmaxf(zm, __shfl_xor(zm, 32, 64));

      const bool skip = __all(zm - m_run <= 10.f);   // defer-max: no rescale
      if (!skip) {
        const float mnew = fmaxf(m_run, zm);
        const float alpha = exp2f(m_run - mnew);
        m_run = mnew;
        l_run *= alpha;
        float a4[4];
        #pragma unroll
        for (int r = 0; r < 4; ++r) a4[r] = __shfl(alpha, lg * 4 + r, 64);
        #pragma unroll
        for (int dn = 0; dn < 4; ++dn)
          #pragma unroll
          for (int r = 0; r < 4; ++r) o_acc[dn][r] *= a4[r];
      }

      float psum = 0.f;
      #pragma unroll
      for (int n = 0; n < 8; ++n) {
        float p0 = exp2f(s[n][0] - m_run); psum += p0;
        float p1 = exp2f(s[n][1] - m_run); psum += p1;
        float p2 = exp2f(s[n][2] - m_run); psum += p2;
        float p3 = exp2f(s[n][3] - m_run); psum += p3;
        bf16x4 pw = { (__bf16)p0, (__bf16)p1, (__bf16)p2, (__bf16)p3 };
        *(bf16x4*)(&Ps[wave][lr * VPAD + n * 16 + lg * 4]) = pw;
      }
      psum += __shfl_xor(psum, 16, 64);
      psum += __shfl_xor(psum, 32, 64);
      l_run += psum;

      // ---- PV: D[q'=lg*4+r][d'=lr] += P * V ----
      bf16x8 pa[4];
      #pragma unroll
      for (int kk = 0; kk < 4; ++kk)
        pa[kk] = *(const bf16x8*)(&Ps[wave][lr * VPAD + kk * 32 + lg * 8]);
      __builtin_amdgcn_s_setprio(1);
      #pragma unroll
      for (int dn = 0; dn < 4; ++dn) {
        #pragma unroll
        for (int kk = 0; kk < 4; ++kk) {
          const bf16x8 vf = *(const bf16x8*)(Vs + (dn * 16 + lr) * VPAD + kk * 32 + lg * 8);
          o_acc[dn] = __builtin_amdgcn_mfma_f32_16x16x32_bf16(pa[kk], vf, o_acc[dn], 0, 0, 0);
        }
      }
      __builtin_amdgcn_s_setprio(0);
    }
  }

  // ---- epilogue ----
  float linv[4];
  #pragma unroll
  for (int r = 0; r < 4; ++r) linv[r] = 1.f / __shfl(l_run, lg * 4 + r, 64);
  #pragma unroll
  for (int r = 0; r < 4; ++r) {
    const int qq = q0 + wv * 16 + lg * 4 + r;
    const size_t obase = ((size_t)(b * SEQ + qq)) * 1024 + h * 64;
    #pragma unroll
    for (int dn = 0; dn < 4; ++dn)
      o[obase + dn * 16 + lr] = f2bf(o_acc[dn][r] * linv[r]);
  }
}

extern "C" void kernel_launch(void* const* d_in, const int* in_sizes, int n_in,
                              void* d_out, int out_size, void* d_ws, size_t ws_size,
                              hipStream_t stream) {
  const float* x    = (const float*)d_in[0];
  const float* Wq   = (const float*)d_in[2];
  const float* Wk   = (const float*)d_in[3];
  const float* Wv   = (const float*)d_in[4];
  const float* Wo   = (const float*)d_in[5];
  const float* bo   = (const float*)d_in[6];
  const float* W1   = (const float*)d_in[7];
  const float* b1   = (const float*)d_in[8];
  const float* W2   = (const float*)d_in[9];
  const float* b2   = (const float*)d_in[10];
  const float* ln1w = (const float*)d_in[11];
  const float* ln1b = (const float*)d_in[12];
  const float* ln2w = (const float*)d_in[13];
  const float* ln2b = (const float*)d_in[14];

  char* ws = (char*)d_ws;
  unsigned short* WqkvT = (unsigned short*)(ws);             // [3072][1024] bf16
  unsigned short* WoT   = (unsigned short*)(ws + 6291456);   // [1024][1024]
  unsigned short* W1T   = (unsigned short*)(ws + 8388608);   // [4096][1024]
  unsigned short* W2T   = (unsigned short*)(ws + 16777216);  // [1024][4096]
  unsigned short* xn    = (unsigned short*)(ws + 25165824);  // [4096][1024]
  unsigned short* x1h   = (unsigned short*)(ws + 33554432);  // [4096][1024] bf16 residual
  unsigned short* qkv   = (unsigned short*)(ws + 50331648);  // [4096][3072]
  unsigned short* oc    = (unsigned short*)(ws + 75497472);  // [4096][1024]
  unsigned short* hbuf  = qkv;                               // aliases qkv+oc

  convw_all<<<3072, 256, 0, stream>>>(Wq, Wk, Wv, Wo, W1, W2, WqkvT, WoT, W1T, W2T);
  ln_kernel<false><<<4096, 256, 0, stream>>>(x, ln1w, ln1b, xn);
  gemm256v2<0><<<dim3(12, 16), 512, 0, stream>>>(xn, WqkvT, qkv, nullptr, 4096, 3072, 1024);
  attn_mfma<<<512, 512, 0, stream>>>(qkv, oc);
  gemm_kp<2><<<dim3(8, 32), 256, 0, stream>>>(oc, WoT, x1h, bo, x, nullptr, 4096, 1024, 1024);
  ln_kernel<true><<<4096, 256, 0, stream>>>(x1h, ln2w, ln2b, xn);
  gemm256v2<2><<<dim3(16, 16), 512, 0, stream>>>(xn, W1T, hbuf, b1, 4096, 4096, 1024);
  gemm_kp<3><<<dim3(8, 32), 256, 0, stream>>>(hbuf, W2T, (float*)d_out, b2, nullptr, x1h, 4096, 1024, 4096);
}

// Round 19
// 215.727 us; speedup vs baseline: 1.0380x; 1.0380x over previous
//
#include <hip/hip_runtime.h>
#include <hip/hip_bf16.h>
#include <stdint.h>

#define DEV static __device__ __forceinline__

using f32x4  = __attribute__((ext_vector_type(4))) float;
using bf16x4 = __attribute__((ext_vector_type(4))) __bf16;
using bf16x8 = __attribute__((ext_vector_type(8))) __bf16;

constexpr int SEQ = 2048;

DEV unsigned short f2bf(float f) {
  union { float f; unsigned u; } c; c.f = f;
  unsigned u = c.u;
  u += 0x7fffu + ((u >> 16) & 1u);   // RNE
  return (unsigned short)(u >> 16);
}
DEV float bf2f(unsigned short h) {
  union { unsigned u; float f; } c; c.u = ((unsigned)h) << 16;
  return c.f;
}

DEV float wred_sum(float v) {
  #pragma unroll
  for (int m = 32; m > 0; m >>= 1) v += __shfl_xor(v, m, 64);
  return v;
}

// async global->LDS, 16B per lane. LDS dest = wave-uniform base + lane*16.
DEV void g2l16(const unsigned short* g, unsigned short* l) {
  __builtin_amdgcn_global_load_lds(
      (const __attribute__((address_space(1))) void*)g,
      (__attribute__((address_space(3))) void*)l, 16, 0, 0);
}

// T1: bijective chunked XCD swizzle (requires nwg % 8 == 0)
DEV int xcd_map(int bid, int nwg) {
  const int cpx = nwg >> 3;
  return (bid & 7) * cpx + (bid >> 3);
}

// ---------------- ALL weight transposes, one dispatch, 64x64 tiles ----------
__global__ __launch_bounds__(256) void convw_all(
    const float* __restrict__ Wq, const float* __restrict__ Wk,
    const float* __restrict__ Wv, const float* __restrict__ Wo,
    const float* __restrict__ W1, const float* __restrict__ W2,
    unsigned short* __restrict__ WqkvT, unsigned short* __restrict__ WoT,
    unsigned short* __restrict__ W1T,   unsigned short* __restrict__ W2T)
{
  const int blk = blockIdx.x;
  const float* inh; unsigned short* outh; int K, Nh, n0, k0;
  if (blk < 768) {
    const int seg = blk >> 8, l = blk & 255;       // 16 heads x 16 k-tiles
    const int head = l >> 4, kt = l & 15;
    const float* in = seg == 0 ? Wq : seg == 1 ? Wk : Wv;
    inh  = in + (size_t)head * 1024 * 64;
    outh = WqkvT + (size_t)seg * 1024 * 1024 + (size_t)head * 64 * 1024;
    K = 1024; Nh = 64; n0 = 0; k0 = kt * 64;
  } else if (blk < 1024) {
    const int l = blk - 768; inh = Wo; outh = WoT; K = 1024; Nh = 1024;
    n0 = (l & 15) * 64; k0 = (l >> 4) * 64;
  } else if (blk < 2048) {
    const int l = blk - 1024; inh = W1; outh = W1T; K = 1024; Nh = 4096;
    n0 = (l & 63) * 64; k0 = (l >> 6) * 64;
  } else {
    const int l = blk - 2048; inh = W2; outh = W2T; K = 4096; Nh = 1024;
    n0 = (l & 15) * 64; k0 = (l >> 4) * 64;
  }
  __shared__ float t[64][65];
  const int tid = threadIdx.x;
  #pragma unroll
  for (int r = 0; r < 4; ++r) {
    const int idx = tid + 256 * r;
    const int k = idx >> 4, c = (idx & 15) * 4;
    const float4 v = *(const float4*)(inh + (size_t)(k0 + k) * Nh + n0 + c);
    t[c + 0][k] = v.x; t[c + 1][k] = v.y; t[c + 2][k] = v.z; t[c + 3][k] = v.w;
  }
  __syncthreads();
  #pragma unroll
  for (int r = 0; r < 4; ++r) {
    const int idx = tid + 256 * r;
    const int n = idx >> 4, k4 = (idx & 15) * 4;
    ushort4 o;
    o.x = f2bf(t[n][k4 + 0]); o.y = f2bf(t[n][k4 + 1]);
    o.z = f2bf(t[n][k4 + 2]); o.w = f2bf(t[n][k4 + 3]);
    *(ushort4*)(outh + (size_t)(n0 + n) * K + k0 + k4) = o;
  }
}

// ---------------- LayerNorm -> bf16 out (templated input dtype) -------------
template<bool BF16IN>
__global__ __launch_bounds__(256) void ln_kernel(
    const void* __restrict__ xin, const float* __restrict__ w,
    const float* __restrict__ b, unsigned short* __restrict__ out)
{
  const int row = blockIdx.x;
  const int tid = threadIdx.x;
  float4 v;
  if (BF16IN) {
    const ushort4 u = ((const ushort4*)((const unsigned short*)xin + (size_t)row * 1024))[tid];
    v.x = bf2f(u.x); v.y = bf2f(u.y); v.z = bf2f(u.z); v.w = bf2f(u.w);
  } else {
    v = ((const float4*)((const float*)xin + (size_t)row * 1024))[tid];
  }
  float s  = v.x + v.y + v.z + v.w;
  float s2 = v.x*v.x + v.y*v.y + v.z*v.z + v.w*v.w;
  s = wred_sum(s); s2 = wred_sum(s2);
  __shared__ float rs[4], rs2[4];
  const int wave = tid >> 6, lane = tid & 63;
  if (lane == 0) { rs[wave] = s; rs2[wave] = s2; }
  __syncthreads();
  const float S  = rs[0] + rs[1] + rs[2] + rs[3];
  const float S2 = rs2[0] + rs2[1] + rs2[2] + rs2[3];
  const float mean = S * (1.f / 1024.f);
  const float var  = S2 * (1.f / 1024.f) - mean * mean;
  const float inv  = rsqrtf(var + 1e-5f);
  const float4 wv = ((const float4*)w)[tid];
  const float4 bv = ((const float4*)b)[tid];
  ushort4 o;
  o.x = f2bf((v.x - mean) * inv * wv.x + bv.x);
  o.y = f2bf((v.y - mean) * inv * wv.y + bv.y);
  o.z = f2bf((v.z - mean) * inv * wv.z + bv.z);
  o.w = f2bf((v.w - mean) * inv * wv.w + bv.w);
  ((ushort4*)(out + (size_t)row * 1024))[tid] = o;
}

// ---------------- 128x64 K-pipelined GEMM, BK=64 (Wo / FFN2) ----------------
// R17 configuration (measured best): 4 waves of 64x32, 3-slot LDS = 72 KB
// -> 2 blocks/CU (2 waves/SIMD TLP), counted vmcnt(6), one raw barrier/iter.
// R14+R18 lesson: >=2 waves/SIMD beats better MFMA:ds_read ratio at 1/SIMD.
// EPI 2: bf16 out = acc + bias + fp32 res   (Wo -> x1h)
// EPI 3: fp32 out = acc + bias + bf16 res   (FFN2 -> d_out)
template<int EPI>
__global__ __launch_bounds__(256) void gemm_kp(
    const unsigned short* __restrict__ A, const unsigned short* __restrict__ BT,
    void* __restrict__ Cout, const float* __restrict__ bias,
    const float* __restrict__ resf, const unsigned short* __restrict__ resh,
    int M, int N, int K)
{
  __shared__ unsigned short sA[3][128 * 64];
  __shared__ unsigned short sB[3][64 * 64];
  const int tid = threadIdx.x;
  const int wave = tid >> 6, lane = tid & 63;
  const int wr = wave >> 1, wc = wave & 1;       // 2x2 waves -> 64x32 each
  const int bid = xcd_map(blockIdx.y * gridDim.x + blockIdx.x, gridDim.x * gridDim.y);
  const int m0 = (bid / gridDim.x) * 128, n0 = (bid % gridDim.x) * 64;
  const int lr = lane & 15, lg = lane >> 4;
  const int wb = tid & 192;                      // wave*64 (uniform)

  const f32x4 zero = {0.f, 0.f, 0.f, 0.f};
  f32x4 acc[4][2];
  #pragma unroll
  for (int i = 0; i < 4; ++i)
    #pragma unroll
    for (int j = 0; j < 2; ++j) acc[i][j] = zero;

  auto STAGE = [&](int slot, int kt) {
    const int k0 = kt * 64;
    #pragma unroll
    for (int r = 0; r < 4; ++r) {
      const int c = tid + 256 * r;
      const int row = c >> 3;
      const int so = ((c & 7) ^ (row & 7)) * 8;
      g2l16(A + (size_t)(m0 + row) * K + k0 + so, sA[slot] + (size_t)(wb + 256 * r) * 8);
    }
    #pragma unroll
    for (int r = 0; r < 2; ++r) {
      const int c = tid + 256 * r;
      const int row = c >> 3;
      const int so = ((c & 7) ^ (row & 7)) * 8;
      g2l16(BT + (size_t)(n0 + row) * K + k0 + so, sB[slot] + (size_t)(wb + 256 * r) * 8);
    }
  };

  const int nt = K / 64;
  STAGE(0, 0); STAGE(1, 1);

  for (int t = 0; t < nt; ++t) {
    asm volatile("s_waitcnt vmcnt(6)" ::: "memory");   // stage t landed (6 loads/stage)
    __builtin_amdgcn_s_barrier();                      // all waves' loads in
    const int slot = t % 3;
    bf16x8 af[4][2], bfr[2][2];
    #pragma unroll
    for (int i = 0; i < 4; ++i) {
      const int row = wr * 64 + i * 16 + lr;
      #pragma unroll
      for (int kk = 0; kk < 2; ++kk)
        af[i][kk] = *(const bf16x8*)(sA[slot] + row * 64 + (((kk * 4 + lg) ^ (row & 7)) << 3));
    }
    #pragma unroll
    for (int j = 0; j < 2; ++j) {
      const int row = wc * 32 + j * 16 + lr;
      #pragma unroll
      for (int kk = 0; kk < 2; ++kk)
        bfr[j][kk] = *(const bf16x8*)(sB[slot] + row * 64 + (((kk * 4 + lg) ^ (row & 7)) << 3));
    }
    __builtin_amdgcn_s_setprio(1);
    #pragma unroll
    for (int i = 0; i < 4; ++i)
      #pragma unroll
      for (int j = 0; j < 2; ++j)
        #pragma unroll
        for (int kk = 0; kk < 2; ++kk)
          acc[i][j] = __builtin_amdgcn_mfma_f32_16x16x32_bf16(af[i][kk], bfr[j][kk], acc[i][j], 0, 0, 0);
    __builtin_amdgcn_s_setprio(0);
    const int nx = (t + 2 < nt) ? t + 2 : nt - 1;      // clamped tail
    STAGE((t + 2) % 3, nx);
  }
  asm volatile("s_waitcnt vmcnt(0)" ::: "memory");

  #pragma unroll
  for (int i = 0; i < 4; ++i) {
    #pragma unroll
    for (int j = 0; j < 2; ++j) {
      #pragma unroll
      for (int r = 0; r < 4; ++r) {
        const int row = m0 + wr * 64 + i * 16 + lg * 4 + r;
        const int col = n0 + wc * 32 + j * 16 + lr;
        const float v = acc[i][j][r];
        if (EPI == 2) {
          ((unsigned short*)Cout)[(size_t)row * N + col] =
              f2bf(v + bias[col] + resf[(size_t)row * N + col]);
        } else {
          ((float*)Cout)[(size_t)row * N + col] =
              v + bias[col] + bf2f(resh[(size_t)row * N + col]);
        }
      }
    }
  }
}

// ---------------- 256x256 3-slot K-pipelined GEMM, BK=32 (QKV / FFN1) -------
template<int EPI>
__global__ __launch_bounds__(512) void gemm256v2(
    const unsigned short* __restrict__ A, const unsigned short* __restrict__ BT,
    void* __restrict__ Cout, const float* __restrict__ bias,
    int M, int N, int K)
{
  __shared__ unsigned short sA[3][256 * 32];
  __shared__ unsigned short sB[3][256 * 32];
  const int tid = threadIdx.x;
  const int wave = tid >> 6, lane = tid & 63;
  const int wm = wave >> 2, wn = wave & 3;       // 2x4 waves -> 128x64 each
  const int bid = xcd_map(blockIdx.y * gridDim.x + blockIdx.x, gridDim.x * gridDim.y);
  const int m0 = (bid / gridDim.x) * 256, n0 = (bid % gridDim.x) * 256;
  const int lr = lane & 15, lg = lane >> 4;
  const int wb = tid & 448;                      // wave*64 (uniform)

  const f32x4 zero = {0.f, 0.f, 0.f, 0.f};
  f32x4 acc[8][4];
  #pragma unroll
  for (int i = 0; i < 8; ++i)
    #pragma unroll
    for (int j = 0; j < 4; ++j) acc[i][j] = zero;

  auto STAGE = [&](int slot, int kt) {
    const int k0 = kt * 32;
    #pragma unroll
    for (int r = 0; r < 2; ++r) {
      const int c = tid + 512 * r;
      const int row = c >> 2;
      const int so = ((c & 3) ^ (row & 3)) * 8;
      const int cb = wb + 512 * r;
      g2l16(A  + (size_t)(m0 + row) * K + k0 + so, sA[slot] + (size_t)cb * 8);
      g2l16(BT + (size_t)(n0 + row) * K + k0 + so, sB[slot] + (size_t)cb * 8);
    }
  };

  const int nt = K / 32;
  STAGE(0, 0); STAGE(1, 1);

  for (int t = 0; t < nt; ++t) {
    asm volatile("s_waitcnt vmcnt(4)" ::: "memory");   // stage t landed (4 loads/stage)
    __builtin_amdgcn_s_barrier();                      // all waves' loads in
    const int slot = t % 3;
    bf16x8 af[8], bfr[4];
    #pragma unroll
    for (int i = 0; i < 8; ++i) {
      const int row = wm * 128 + i * 16 + lr;
      af[i] = *(const bf16x8*)(sA[slot] + row * 32 + ((lg ^ (row & 3)) << 3));
    }
    #pragma unroll
    for (int j = 0; j < 4; ++j) {
      const int row = wn * 64 + j * 16 + lr;
      bfr[j] = *(const bf16x8*)(sB[slot] + row * 32 + ((lg ^ (row & 3)) << 3));
    }
    __builtin_amdgcn_s_setprio(1);
    #pragma unroll
    for (int i = 0; i < 8; ++i)
      #pragma unroll
      for (int j = 0; j < 4; ++j)
        acc[i][j] = __builtin_amdgcn_mfma_f32_16x16x32_bf16(af[i], bfr[j], acc[i][j], 0, 0, 0);
    __builtin_amdgcn_s_setprio(0);
    const int nx = (t + 2 < nt) ? t + 2 : nt - 1;      // clamped tail
    STAGE((t + 2) % 3, nx);
  }
  asm volatile("s_waitcnt vmcnt(0)" ::: "memory");

  #pragma unroll
  for (int i = 0; i < 8; ++i) {
    #pragma unroll
    for (int j = 0; j < 4; ++j) {
      #pragma unroll
      for (int r = 0; r < 4; ++r) {
        const int row = m0 + wm * 128 + i * 16 + lg * 4 + r;
        const int col = n0 + wn * 64 + j * 16 + lr;
        float v = acc[i][j][r];
        if (EPI == 0) {
          if (col < 1024) v *= 0.18033688f;   // fold attn scale into Q
          ((unsigned short*)Cout)[(size_t)row * N + col] = f2bf(v);
        } else {
          float t2 = v + bias[col];
          t2 = t2 > 0.f ? t2 : 0.f;
          ((unsigned short*)Cout)[(size_t)row * N + col] = f2bf(t2);
        }
      }
    }
  }
}

// ---------------- MFMA flash attention (8-wave, merged q-pair) ----------------
constexpr int VPAD = 136;   // V/P row stride: 128 keys + 8

__global__ __launch_bounds__(512) void attn_mfma(
    const unsigned short* __restrict__ qkv, unsigned short* __restrict__ o)
{
  const int p  = blockIdx.x >> 5;          // 0..15 (p=0 heaviest, first)
  const int bh = blockIdx.x & 31;
  const int b = bh >> 4, h = bh & 15;
  const int tid = threadIdx.x;
  const int wave = tid >> 6, lane = tid & 63;
  const int grp = wave >> 2, wv = wave & 3;
  const int lr = lane & 15, lg = lane >> 4;

  const int qi = grp ? p : (31 - p);       // grp0 = long group
  const int mynt = (qi >> 1) + 1;          // causal 128-key tiles for this group
  const int nt_long = ((31 - p) >> 1) + 1; // block loop count
  const int q0 = qi * 64;

  __shared__ unsigned short Ks[128 * 64];      // linear, XOR-swizzled cols
  __shared__ unsigned short Vs[64 * VPAD];     // Vs[d][key] (transposed)
  __shared__ unsigned short Ps[8][16 * VPAD];  // per-wave P tile [q][key]

  const size_t qbase = ((size_t)(b * SEQ + q0 + wv * 16 + lr)) * 3072 + h * 64;
  bf16x8 qb[2];
  qb[0] = *(const bf16x8*)(qkv + qbase + lg * 8);
  qb[1] = *(const bf16x8*)(qkv + qbase + 32 + lg * 8);

  const f32x4 zero = {0.f, 0.f, 0.f, 0.f};
  f32x4 o_acc[4];
  #pragma unroll
  for (int dn = 0; dn < 4; ++dn) o_acc[dn] = zero;
  float m_run = -1e30f, l_run = 0.f;       // per-lane: q-row = lr

  for (int t = 0; t < nt_long; ++t) {
    const int j0 = t * 128;
    __syncthreads();                       // protect prev-tile reads
    #pragma unroll
    for (int r = 0; r < 2; ++r) {
      const int c = tid + 512 * r;
      const int row = c >> 3;
      const int slot = (c & 7) ^ (row & 7);
      const size_t gsrc = ((size_t)(b * SEQ + j0 + row)) * 3072 + 1024 + h * 64 + slot * 8;
      g2l16(qkv + gsrc, Ks + (size_t)((tid & 448) + 512 * r) * 8);
    }
    #pragma unroll
    for (int r = 0; r < 2; ++r) {
      const int c = tid + 512 * r;
      const int key = c & 127, dseg = c >> 7;
      const size_t base = ((size_t)(b * SEQ + j0 + key)) * 3072 + 2048 + h * 64 + dseg * 8;
      int4 rv = *(const int4*)(qkv + base);
      const unsigned short* u = (const unsigned short*)&rv;
      #pragma unroll
      for (int e = 0; e < 8; ++e) Vs[(dseg * 8 + e) * VPAD + key] = u[e];
    }
    __syncthreads();                       // staging visible (vmcnt+lgkm drain)

    if (t < mynt) {                        // group-uniform causal gate
      // ---- QK^T swapped: D[key'=lg*4+r][q'=lr] = mfma(K, Q) ----
      f32x4 s[8];
      __builtin_amdgcn_s_setprio(1);
      #pragma unroll
      for (int n = 0; n < 8; ++n) {
        const int row = n * 16 + lr;
        const bf16x8 kf0 = *(const bf16x8*)(Ks + row * 64 + ((lg ^ (row & 7)) << 3));
        const bf16x8 kf1 = *(const bf16x8*)(Ks + row * 64 + (((4 + lg) ^ (row & 7)) << 3));
        s[n] = __builtin_amdgcn_mfma_f32_16x16x32_bf16(kf0, qb[0], zero, 0, 0, 0);
        s[n] = __builtin_amdgcn_mfma_f32_16x16x32_bf16(kf1, qb[1], s[n], 0, 0, 0);
      }
      __builtin_amdgcn_s_setprio(0);

      // ---- online softmax: mask only on diag tile; defer-max (T13) ----
      const bool diag = (t == mynt - 1);
      float zm = -3e38f;
      if (diag) {
        const int q = q0 + wv * 16 + lr;
        const int kbase = j0 + lg * 4;
        #pragma unroll
        for (int n = 0; n < 8; ++n)
          #pragma unroll
          for (int r = 0; r < 4; ++r) {
            float z = s[n][r];
            if (kbase + n * 16 + r > q) z = -3e38f;
            s[n][r] = z;
            zm = fmaxf(zm, z);
          }
      } else {
        #pragma unroll
        for (int n = 0; n < 8; ++n)
          zm = fmaxf(fmaxf(fmaxf(zm, s[n][0]), fmaxf(s[n][1], s[n][2])), s[n][3]);
      }
      zm = fmaxf(zm, __shfl_xor(zm, 16, 64));
      zm = fmaxf(zm, __shfl_xor(zm, 32, 64));

      const bool skip = __all(zm - m_run <= 10.f);   // defer-max: no rescale
      if (!skip) {
        const float mnew = fmaxf(m_run, zm);
        const float alpha = exp2f(m_run - mnew);
        m_run = mnew;
        l_run *= alpha;
        float a4[4];
        #pragma unroll
        for (int r = 0; r < 4; ++r) a4[r] = __shfl(alpha, lg * 4 + r, 64);
        #pragma unroll
        for (int dn = 0; dn < 4; ++dn)
          #pragma unroll
          for (int r = 0; r < 4; ++r) o_acc[dn][r] *= a4[r];
      }

      float psum = 0.f;
      #pragma unroll
      for (int n = 0; n < 8; ++n) {
        float p0 = exp2f(s[n][0] - m_run); psum += p0;
        float p1 = exp2f(s[n][1] - m_run); psum += p1;
        float p2 = exp2f(s[n][2] - m_run); psum += p2;
        float p3 = exp2f(s[n][3] - m_run); psum += p3;
        bf16x4 pw = { (__bf16)p0, (__bf16)p1, (__bf16)p2, (__bf16)p3 };
        *(bf16x4*)(&Ps[wave][lr * VPAD + n * 16 + lg * 4]) = pw;
      }
      psum += __shfl_xor(psum, 16, 64);
      psum += __shfl_xor(psum, 32, 64);
      l_run += psum;

      // ---- PV: D[q'=lg*4+r][d'=lr] += P * V ----
      bf16x8 pa[4];
      #pragma unroll
      for (int kk = 0; kk < 4; ++kk)
        pa[kk] = *(const bf16x8*)(&Ps[wave][lr * VPAD + kk * 32 + lg * 8]);
      __builtin_amdgcn_s_setprio(1);
      #pragma unroll
      for (int dn = 0; dn < 4; ++dn) {
        #pragma unroll
        for (int kk = 0; kk < 4; ++kk) {
          const bf16x8 vf = *(const bf16x8*)(Vs + (dn * 16 + lr) * VPAD + kk * 32 + lg * 8);
          o_acc[dn] = __builtin_amdgcn_mfma_f32_16x16x32_bf16(pa[kk], vf, o_acc[dn], 0, 0, 0);
        }
      }
      __builtin_amdgcn_s_setprio(0);
    }
  }

  // ---- epilogue ----
  float linv[4];
  #pragma unroll
  for (int r = 0; r < 4; ++r) linv[r] = 1.f / __shfl(l_run, lg * 4 + r, 64);
  #pragma unroll
  for (int r = 0; r < 4; ++r) {
    const int qq = q0 + wv * 16 + lg * 4 + r;
    const size_t obase = ((size_t)(b * SEQ + qq)) * 1024 + h * 64;
    #pragma unroll
    for (int dn = 0; dn < 4; ++dn)
      o[obase + dn * 16 + lr] = f2bf(o_acc[dn][r] * linv[r]);
  }
}

extern "C" void kernel_launch(void* const* d_in, const int* in_sizes, int n_in,
                              void* d_out, int out_size, void* d_ws, size_t ws_size,
                              hipStream_t stream) {
  const float* x    = (const float*)d_in[0];
  const float* Wq   = (const float*)d_in[2];
  const float* Wk   = (const float*)d_in[3];
  const float* Wv   = (const float*)d_in[4];
  const float* Wo   = (const float*)d_in[5];
  const float* bo   = (const float*)d_in[6];
  const float* W1   = (const float*)d_in[7];
  const float* b1   = (const float*)d_in[8];
  const float* W2   = (const float*)d_in[9];
  const float* b2   = (const float*)d_in[10];
  const float* ln1w = (const float*)d_in[11];
  const float* ln1b = (const float*)d_in[12];
  const float* ln2w = (const float*)d_in[13];
  const float* ln2b = (const float*)d_in[14];

  char* ws = (char*)d_ws;
  unsigned short* WqkvT = (unsigned short*)(ws);             // [3072][1024] bf16
  unsigned short* WoT   = (unsigned short*)(ws + 6291456);   // [1024][1024]
  unsigned short* W1T   = (unsigned short*)(ws + 8388608);   // [4096][1024]
  unsigned short* W2T   = (unsigned short*)(ws + 16777216);  // [1024][4096]
  unsigned short* xn    = (unsigned short*)(ws + 25165824);  // [4096][1024]
  unsigned short* x1h   = (unsigned short*)(ws + 33554432);  // [4096][1024] bf16 residual
  unsigned short* qkv   = (unsigned short*)(ws + 50331648);  // [4096][3072]
  unsigned short* oc    = (unsigned short*)(ws + 75497472);  // [4096][1024]
  unsigned short* hbuf  = qkv;                               // aliases qkv+oc

  convw_all<<<3072, 256, 0, stream>>>(Wq, Wk, Wv, Wo, W1, W2, WqkvT, WoT, W1T, W2T);
  ln_kernel<false><<<4096, 256, 0, stream>>>(x, ln1w, ln1b, xn);
  gemm256v2<0><<<dim3(12, 16), 512, 0, stream>>>(xn, WqkvT, qkv, nullptr, 4096, 3072, 1024);
  attn_mfma<<<512, 512, 0, stream>>>(qkv, oc);
  gemm_kp<2><<<dim3(16, 32), 256, 0, stream>>>(oc, WoT, x1h, bo, x, nullptr, 4096, 1024, 1024);
  ln_kernel<true><<<4096, 256, 0, stream>>>(x1h, ln2w, ln2b, xn);
  gemm256v2<2><<<dim3(16, 16), 512, 0, stream>>>(xn, W1T, hbuf, b1, 4096, 4096, 1024);
  gemm_kp<3><<<dim3(16, 32), 256, 0, stream>>>(hbuf, W2T, (float*)d_out, b2, nullptr, x1h, 4096, 1024, 4096);
}